// Round 1
// baseline (437.252 us; speedup 1.0000x reference)
//
#include <hip/hip_runtime.h>
#include <hip/hip_bf16.h>
#include <stdint.h>

#define NTOK 4096
#define DM 1024
#define FF 2048
#define F2 4096
#define NEXP 8
#define PAIR_CAP 9216   // 8192 pairs + 8*128 padding headroom

typedef __bf16 bf16x8 __attribute__((ext_vector_type(8)));
typedef float f32x4 __attribute__((ext_vector_type(4)));

__device__ __forceinline__ unsigned short bf16_rne(float f) {
    union { float f; unsigned int u; } v; v.f = f;
    unsigned int u = v.u;
    return (unsigned short)((u + 0x7FFFu + ((u >> 16) & 1u)) >> 16);
}

__device__ __forceinline__ f32x4 MFMA16(bf16x8 a, bf16x8 b, f32x4 c) {
    return __builtin_amdgcn_mfma_f32_16x16x32_bf16(a, b, c, 0, 0, 0);
}

__device__ __forceinline__ void gload16(const void* g, void* l) {
    __builtin_amdgcn_global_load_lds(
        (const __attribute__((address_space(1))) uint32_t*)g,
        (__attribute__((address_space(3))) uint32_t*)l, 16, 0, 0);
}

// ---------------- gating: scores (fp32), top-2 softmax, x -> bf16 ----------------
__global__ __launch_bounds__(64) void k_gate(const float* __restrict__ x,
                                             const float* __restrict__ Wg,
                                             unsigned short* __restrict__ xbf,
                                             int* __restrict__ te, float* __restrict__ tw,
                                             int* __restrict__ cnt) {
    int t = blockIdx.x;
    int l = threadIdx.x;
    const float* xr = x + (size_t)t * DM + l * 16;
    float xv[16];
#pragma unroll
    for (int i = 0; i < 4; ++i) {
        float4 v = ((const float4*)xr)[i];
        xv[4*i+0] = v.x; xv[4*i+1] = v.y; xv[4*i+2] = v.z; xv[4*i+3] = v.w;
    }
    // bf16 copy of x (vectorized store: 2 x uint4 = 32 B/lane)
    unsigned int pk[8];
#pragma unroll
    for (int i = 0; i < 8; ++i)
        pk[i] = (unsigned int)bf16_rne(xv[2*i]) | ((unsigned int)bf16_rne(xv[2*i+1]) << 16);
    uint4* dst = (uint4*)(xbf + (size_t)t * DM + l * 16);
    dst[0] = make_uint4(pk[0], pk[1], pk[2], pk[3]);
    dst[1] = make_uint4(pk[4], pk[5], pk[6], pk[7]);

    float s[NEXP];
#pragma unroll
    for (int e = 0; e < NEXP; ++e) {
        const float* wr = Wg + e * DM + l * 16;
        float acc = 0.f;
#pragma unroll
        for (int i = 0; i < 4; ++i) {
            float4 v = ((const float4*)wr)[i];
            acc += v.x * xv[4*i] + v.y * xv[4*i+1] + v.z * xv[4*i+2] + v.w * xv[4*i+3];
        }
        s[e] = acc;
    }
#pragma unroll
    for (int off = 32; off > 0; off >>= 1) {
#pragma unroll
        for (int e = 0; e < NEXP; ++e) s[e] += __shfl_xor(s[e], off, 64);
    }
    if (l == 0) {
        int e0 = 0; float v0 = s[0];
        for (int e = 1; e < NEXP; ++e) if (s[e] > v0) { v0 = s[e]; e0 = e; }
        int e1 = -1; float v1 = -1e30f;
        for (int e = 0; e < NEXP; ++e) if (e != e0 && s[e] > v1) { v1 = s[e]; e1 = e; }
        float w0 = 1.f / (1.f + __expf(v1 - v0));
        float w1 = 1.f - w0;
        te[2*t] = e0; te[2*t+1] = e1;
        tw[2*t] = w0; tw[2*t+1] = w1;
        atomicAdd(&cnt[e0], 1); atomicAdd(&cnt[e1], 1);
    }
}

// ---------------- padded offsets + pair-array prefill (tok 0, weight 0) ----------------
__global__ __launch_bounds__(256) void k_offs(const int* __restrict__ cnt,
                                              int* __restrict__ cnt_pad, int* __restrict__ off_pad,
                                              int* __restrict__ pair_tok, float* __restrict__ pair_w) {
    if (threadIdx.x == 0) {
        int o = 0;
        for (int e = 0; e < NEXP; ++e) {
            int cp = ((cnt[e] + 127) >> 7) << 7;
            cnt_pad[e] = cp; off_pad[e] = o; o += cp;
        }
    }
    for (int i = threadIdx.x; i < PAIR_CAP; i += 256) { pair_tok[i] = 0; pair_w[i] = 0.f; }
}

__global__ __launch_bounds__(256) void k_place(const int* __restrict__ te, const float* __restrict__ tw,
                                               const int* __restrict__ off_pad, int* __restrict__ cur,
                                               int* __restrict__ pair_tok, float* __restrict__ pair_w, int n) {
    int t = blockIdx.x * 256 + threadIdx.x;
    if (t >= n) return;
#pragma unroll
    for (int j = 0; j < 2; ++j) {
        int e = te[2*t+j];
        int idx = atomicAdd(&cur[e], 1);
        int slot = off_pad[e] + idx;
        pair_tok[slot] = t; pair_w[slot] = tw[2*t+j];
    }
}

// ---------------- GEMM1: hh = silu(Xg @ W1_a) * (Xg @ W1_g), bf16 out ----------------
// tile: BM=128 rows x BN=64 f-cols (both halves), BK=64, 4 waves (2x2), 16x16x32 MFMA
__global__ __launch_bounds__(256, 2) void k_gemm1(const unsigned short* __restrict__ xbf,
                                                  const float* __restrict__ W1,
                                                  const float* __restrict__ b1,
                                                  const int* __restrict__ pair_tok,
                                                  const int* __restrict__ cnt_pad,
                                                  const int* __restrict__ off_pad,
                                                  unsigned short* __restrict__ hh) {
    int e = blockIdx.z;
    if ((int)blockIdx.y * 128 >= cnt_pad[e]) return;
    int row0 = off_pad[e] + blockIdx.y * 128;
    int f0 = blockIdx.x * 64;
    const float* W1e = W1 + (size_t)e * DM * F2;

    __shared__ unsigned short lA[128 * 64];   // gathered X rows, chunk-swizzled content
    __shared__ unsigned short lBa[64 * 72];   // W1 a-half, transposed [n][k], pad 72
    __shared__ unsigned short lBg[64 * 72];   // W1 g-half

    int t = threadIdx.x, w = t >> 6, l = t & 63;
    int wm = w >> 1, wn = w & 1;

    // A staging: per-lane gathered source, pre-swizzled chunk (c' = c ^ (row&7))
    const unsigned short* asrc[4];
    unsigned short* adst[4];
    {
        int c8 = ((l & 7) ^ (l >> 3)) * 8;
#pragma unroll
        for (int q = 0; q < 4; ++q) {
            int r = w * 32 + q * 8 + (l >> 3);
            int tok = pair_tok[row0 + r];
            asrc[q] = xbf + (size_t)tok * DM + c8;
            adst[q] = lA + (w * 32 + q * 8) * 64;   // wave-uniform base
        }
    }
    int kb = t >> 4, nb = t & 15;
    const float* bsrc = W1e + (size_t)kb * F2 + f0 + nb;

    f32x4 aca[4][2], acg[4][2];
#pragma unroll
    for (int m = 0; m < 4; ++m)
#pragma unroll
        for (int fn = 0; fn < 2; ++fn) { aca[m][fn] = (f32x4){0,0,0,0}; acg[m][fn] = (f32x4){0,0,0,0}; }

    float pfa[16], pfg[16];
#pragma unroll
    for (int p = 0; p < 4; ++p)
#pragma unroll
        for (int i = 0; i < 4; ++i) {
            pfa[p*4+i] = bsrc[(size_t)(p*16) * F2 + i*16];
            pfg[p*4+i] = bsrc[(size_t)(p*16) * F2 + i*16 + FF];
        }
#pragma unroll
    for (int q = 0; q < 4; ++q) gload16(asrc[q], adst[q]);

    for (int kt = 0; kt < 16; ++kt) {
        // write B(kt) from prefetch regs (transposed, strided-n => 2-way banks)
#pragma unroll
        for (int p = 0; p < 4; ++p)
#pragma unroll
            for (int i = 0; i < 4; ++i) {
                int idx = (nb + 16*i) * 72 + kb + 16*p;
                lBa[idx] = bf16_rne(pfa[p*4+i]);
                lBg[idx] = bf16_rne(pfg[p*4+i]);
            }
        __syncthreads();
        if (kt < 15) {   // prefetch B(kt+1) while MFMAs run
            const float* bs = bsrc + (size_t)(kt+1) * 64 * F2;
#pragma unroll
            for (int p = 0; p < 4; ++p)
#pragma unroll
                for (int i = 0; i < 4; ++i) {
                    pfa[p*4+i] = bs[(size_t)(p*16) * F2 + i*16];
                    pfg[p*4+i] = bs[(size_t)(p*16) * F2 + i*16 + FF];
                }
        }
        int lr = l & 15, kg = l >> 4;
#pragma unroll
        for (int ks = 0; ks < 2; ++ks) {
            bf16x8 af[4];
#pragma unroll
            for (int m = 0; m < 4; ++m) {
                int row = wm * 64 + m * 16 + lr;
                int byt = row * 128 + ((ks*64 + kg*16) ^ ((row & 7) << 4));
                af[m] = *(const bf16x8*)((const char*)lA + byt);
            }
#pragma unroll
            for (int fn = 0; fn < 2; ++fn) {
                int n = wn * 32 + fn * 16 + lr;
                int off = n * 72 + ks * 32 + kg * 8;
                bf16x8 ba = *(const bf16x8*)(lBa + off);
                bf16x8 bg = *(const bf16x8*)(lBg + off);
#pragma unroll
                for (int m = 0; m < 4; ++m) {
                    aca[m][fn] = MFMA16(af[m], ba, aca[m][fn]);
                    acg[m][fn] = MFMA16(af[m], bg, acg[m][fn]);
                }
            }
        }
        __syncthreads();
        if (kt < 15) {
#pragma unroll
            for (int q = 0; q < 4; ++q) gload16(asrc[q] + (kt+1) * 64, adst[q]);
        }
    }
    // epilogue: SwiGLU, bf16 store
    int lr = l & 15, kg = l >> 4;
#pragma unroll
    for (int m = 0; m < 4; ++m)
#pragma unroll
        for (int fn = 0; fn < 2; ++fn) {
            int col = f0 + wn * 32 + fn * 16 + lr;
            float ba1 = b1[e * F2 + col], bg1 = b1[e * F2 + FF + col];
#pragma unroll
            for (int j = 0; j < 4; ++j) {
                int row = wm * 64 + m * 16 + kg * 4 + j;
                float a = aca[m][fn][j] + ba1;
                float g = acg[m][fn][j] + bg1;
                float sg = a / (1.f + __expf(-a)) * g;
                hh[(size_t)(row0 + row) * FF + col] = bf16_rne(sg);
            }
        }
}

// ---------------- GEMM2: out += w * (hh @ W2 + b2), scatter via atomicAdd ----------------
__global__ __launch_bounds__(256, 2) void k_gemm2(const unsigned short* __restrict__ hh,
                                                  const float* __restrict__ W2,
                                                  const float* __restrict__ b2,
                                                  const int* __restrict__ pair_tok,
                                                  const float* __restrict__ pair_w,
                                                  const int* __restrict__ cnt_pad,
                                                  const int* __restrict__ off_pad,
                                                  float* __restrict__ out) {
    int e = blockIdx.z;
    if ((int)blockIdx.y * 128 >= cnt_pad[e]) return;
    int row0 = off_pad[e] + blockIdx.y * 128;
    int d0 = blockIdx.x * 64;
    const float* W2e = W2 + (size_t)e * FF * DM;

    __shared__ unsigned short lA[128 * 64];
    __shared__ unsigned short lB[64 * 72];

    int t = threadIdx.x, w = t >> 6, l = t & 63;
    int wm = w >> 1, wn = w & 1;

    const unsigned short* asrc[4];
    unsigned short* adst[4];
    {
        int c8 = ((l & 7) ^ (l >> 3)) * 8;
#pragma unroll
        for (int q = 0; q < 4; ++q) {
            int r = w * 32 + q * 8 + (l >> 3);
            asrc[q] = hh + (size_t)(row0 + r) * FF + c8;
            adst[q] = lA + (w * 32 + q * 8) * 64;
        }
    }
    int kb = t >> 4, nb = t & 15;
    const float* bsrc = W2e + (size_t)kb * DM + d0 + nb;

    f32x4 ac[4][2];
#pragma unroll
    for (int m = 0; m < 4; ++m)
#pragma unroll
        for (int fn = 0; fn < 2; ++fn) ac[m][fn] = (f32x4){0,0,0,0};

    float pf[16];
#pragma unroll
    for (int p = 0; p < 4; ++p)
#pragma unroll
        for (int i = 0; i < 4; ++i) pf[p*4+i] = bsrc[(size_t)(p*16) * DM + i*16];
#pragma unroll
    for (int q = 0; q < 4; ++q) gload16(asrc[q], adst[q]);

    for (int kt = 0; kt < 32; ++kt) {
#pragma unroll
        for (int p = 0; p < 4; ++p)
#pragma unroll
            for (int i = 0; i < 4; ++i)
                lB[(nb + 16*i) * 72 + kb + 16*p] = bf16_rne(pf[p*4+i]);
        __syncthreads();
        if (kt < 31) {
            const float* bs = bsrc + (size_t)(kt+1) * 64 * DM;
#pragma unroll
            for (int p = 0; p < 4; ++p)
#pragma unroll
                for (int i = 0; i < 4; ++i) pf[p*4+i] = bs[(size_t)(p*16) * DM + i*16];
        }
        int lr = l & 15, kg = l >> 4;
#pragma unroll
        for (int ks = 0; ks < 2; ++ks) {
            bf16x8 af[4];
#pragma unroll
            for (int m = 0; m < 4; ++m) {
                int row = wm * 64 + m * 16 + lr;
                int byt = row * 128 + ((ks*64 + kg*16) ^ ((row & 7) << 4));
                af[m] = *(const bf16x8*)((const char*)lA + byt);
            }
#pragma unroll
            for (int fn = 0; fn < 2; ++fn) {
                int n = wn * 32 + fn * 16 + lr;
                bf16x8 bb = *(const bf16x8*)(lB + n * 72 + ks * 32 + kg * 8);
#pragma unroll
                for (int m = 0; m < 4; ++m) ac[m][fn] = MFMA16(af[m], bb, ac[m][fn]);
            }
        }
        __syncthreads();
        if (kt < 31) {
#pragma unroll
            for (int q = 0; q < 4; ++q) gload16(asrc[q] + (kt+1) * 64, adst[q]);
        }
    }
    int lr = l & 15, kg = l >> 4;
#pragma unroll
    for (int m = 0; m < 4; ++m)
#pragma unroll
        for (int fn = 0; fn < 2; ++fn) {
            int col = d0 + wn * 32 + fn * 16 + lr;
            float b2v = b2[e * DM + col];
#pragma unroll
            for (int j = 0; j < 4; ++j) {
                int row = wm * 64 + m * 16 + kg * 4 + j;
                int pr = row0 + row;
                int tok = pair_tok[pr];
                float wt = pair_w[pr];
                atomicAdd(out + (size_t)tok * DM + col, wt * (ac[m][fn][j] + b2v));
            }
        }
}

// ---------------- host ----------------
extern "C" void kernel_launch(void* const* d_in, const int* in_sizes, int n_in,
                              void* d_out, int out_size, void* d_ws, size_t ws_size,
                              hipStream_t stream) {
    const float* x  = (const float*)d_in[0];
    const float* Wg = (const float*)d_in[1];
    const float* W1 = (const float*)d_in[2];
    const float* b1 = (const float*)d_in[3];
    const float* W2 = (const float*)d_in[4];
    const float* b2 = (const float*)d_in[5];
    float* out = (float*)d_out;

    char* ws = (char*)d_ws;
    unsigned short* xbf = (unsigned short*)ws;                       // 8 MB
    unsigned short* hh  = (unsigned short*)(ws + 8388608);           // 36 MB
    int*   pair_tok = (int*)(ws + 46137344);
    float* pair_w   = (float*)(ws + 46174208);
    int*   te       = (int*)(ws + 46211072);
    float* tw       = (float*)(ws + 46243840);
    int*   cnt      = (int*)(ws + 46276608);
    int*   cur      = (int*)(ws + 46276640);
    int*   cnt_pad  = (int*)(ws + 46276672);
    int*   off_pad  = (int*)(ws + 46276704);

    hipMemsetAsync(d_out, 0, (size_t)out_size * sizeof(float), stream);
    hipMemsetAsync(cnt, 0, 64, stream);  // cnt + cur

    k_gate<<<NTOK, 64, 0, stream>>>(x, Wg, xbf, te, tw, cnt);
    k_offs<<<1, 256, 0, stream>>>(cnt, cnt_pad, off_pad, pair_tok, pair_w);
    k_place<<<(NTOK + 255) / 256, 256, 0, stream>>>(te, tw, off_pad, cur, pair_tok, pair_w, NTOK);
    k_gemm1<<<dim3(32, 32, 8), 256, 0, stream>>>(xbf, W1, b1, pair_tok, cnt_pad, off_pad, hh);
    k_gemm2<<<dim3(16, 32, 8), 256, 0, stream>>>(hh, W2, b2, pair_tok, pair_w, cnt_pad, off_pad, out);
}

// Round 3
// 424.011 us; speedup vs baseline: 1.0312x; 1.0312x over previous
//
#include <hip/hip_runtime.h>
#include <hip/hip_bf16.h>
#include <stdint.h>

#define NTOK 4096
#define DM 1024
#define FF 2048
#define F2 4096
#define NEXP 8
#define PAIR_CAP 9216   // 8192 pairs + 8*128 padding headroom

typedef __bf16 bf16x8 __attribute__((ext_vector_type(8)));
typedef float f32x4 __attribute__((ext_vector_type(4)));

__device__ __forceinline__ unsigned short bf16_rne(float f) {
    union { float f; unsigned int u; } v; v.f = f;
    unsigned int u = v.u;
    return (unsigned short)((u + 0x7FFFu + ((u >> 16) & 1u)) >> 16);
}

__device__ __forceinline__ f32x4 MFMA16(bf16x8 a, bf16x8 b, f32x4 c) {
    return __builtin_amdgcn_mfma_f32_16x16x32_bf16(a, b, c, 0, 0, 0);
}

__device__ __forceinline__ void gload16(const void* g, void* l) {
    __builtin_amdgcn_global_load_lds(
        (const __attribute__((address_space(1))) uint32_t*)g,
        (__attribute__((address_space(3))) uint32_t*)l, 16, 0, 0);
}

// ---------------- gating: scores (fp32), top-2 softmax, x -> bf16 ----------------
__global__ __launch_bounds__(64) void k_gate(const float* __restrict__ x,
                                             const float* __restrict__ Wg,
                                             unsigned short* __restrict__ xbf,
                                             int* __restrict__ te, float* __restrict__ tw,
                                             int* __restrict__ cnt) {
    int t = blockIdx.x;
    int l = threadIdx.x;
    const float* xr = x + (size_t)t * DM + l * 16;
    float xv[16];
#pragma unroll
    for (int i = 0; i < 4; ++i) {
        float4 v = ((const float4*)xr)[i];
        xv[4*i+0] = v.x; xv[4*i+1] = v.y; xv[4*i+2] = v.z; xv[4*i+3] = v.w;
    }
    unsigned int pk[8];
#pragma unroll
    for (int i = 0; i < 8; ++i)
        pk[i] = (unsigned int)bf16_rne(xv[2*i]) | ((unsigned int)bf16_rne(xv[2*i+1]) << 16);
    uint4* dst = (uint4*)(xbf + (size_t)t * DM + l * 16);
    dst[0] = make_uint4(pk[0], pk[1], pk[2], pk[3]);
    dst[1] = make_uint4(pk[4], pk[5], pk[6], pk[7]);

    float s[NEXP];
#pragma unroll
    for (int e = 0; e < NEXP; ++e) {
        const float* wr = Wg + e * DM + l * 16;
        float acc = 0.f;
#pragma unroll
        for (int i = 0; i < 4; ++i) {
            float4 v = ((const float4*)wr)[i];
            acc += v.x * xv[4*i] + v.y * xv[4*i+1] + v.z * xv[4*i+2] + v.w * xv[4*i+3];
        }
        s[e] = acc;
    }
#pragma unroll
    for (int off = 32; off > 0; off >>= 1) {
#pragma unroll
        for (int e = 0; e < NEXP; ++e) s[e] += __shfl_xor(s[e], off, 64);
    }
    if (l == 0) {
        int e0 = 0; float v0 = s[0];
        for (int e = 1; e < NEXP; ++e) if (s[e] > v0) { v0 = s[e]; e0 = e; }
        int e1 = -1; float v1 = -1e30f;
        for (int e = 0; e < NEXP; ++e) if (e != e0 && s[e] > v1) { v1 = s[e]; e1 = e; }
        float w0 = 1.f / (1.f + __expf(v1 - v0));
        float w1 = 1.f - w0;
        te[2*t] = e0; te[2*t+1] = e1;
        tw[2*t] = w0; tw[2*t+1] = w1;
        atomicAdd(&cnt[e0], 1); atomicAdd(&cnt[e1], 1);
    }
}

// ---------------- padded offsets + pair-array prefill (tok 0, weight 0) ----------------
__global__ __launch_bounds__(256) void k_offs(const int* __restrict__ cnt,
                                              int* __restrict__ cnt_pad, int* __restrict__ off_pad,
                                              int* __restrict__ pair_tok, float* __restrict__ pair_w) {
    if (threadIdx.x == 0) {
        int o = 0;
        for (int e = 0; e < NEXP; ++e) {
            int cp = ((cnt[e] + 127) >> 7) << 7;
            cnt_pad[e] = cp; off_pad[e] = o; o += cp;
        }
    }
    for (int i = threadIdx.x; i < PAIR_CAP; i += 256) { pair_tok[i] = 0; pair_w[i] = 0.f; }
}

__global__ __launch_bounds__(256) void k_place(const int* __restrict__ te, const float* __restrict__ tw,
                                               const int* __restrict__ off_pad, int* __restrict__ cur,
                                               int* __restrict__ pair_tok, float* __restrict__ pair_w, int n) {
    int t = blockIdx.x * 256 + threadIdx.x;
    if (t >= n) return;
#pragma unroll
    for (int j = 0; j < 2; ++j) {
        int e = te[2*t+j];
        int idx = atomicAdd(&cur[e], 1);
        int slot = off_pad[e] + idx;
        pair_tok[slot] = t; pair_w[slot] = tw[2*t+j];
    }
}

// ---------------- cvt1: W1 fp32 [e][1024k][4096f] -> W1T_h bf16 [e][2048n][1024k] ----------------
// half h: n<1024 -> a-col (h*1024+n); n>=1024 -> g-col (FF + h*1024 + n-1024)
__global__ __launch_bounds__(256) void k_cvt1(const float* __restrict__ W1,
                                              unsigned short* __restrict__ WT, int h) {
    __shared__ float lt[64][65];
    int e = blockIdx.z, nt = blockIdx.y, kt = blockIdx.x;
    int col0 = (nt < 16) ? (h * 1024 + nt * 64) : (FF + h * 1024 + (nt - 16) * 64);
    const float* src = W1 + (size_t)e * DM * F2 + (size_t)(kt * 64) * F2 + col0;
    int t = threadIdx.x;
#pragma unroll
    for (int i = 0; i < 4; ++i) {
        int flat = i * 256 + t;
        int k = flat >> 4, c4 = (flat & 15) * 4;
        float4 v = *(const float4*)(src + (size_t)k * F2 + c4);
        lt[k][c4] = v.x; lt[k][c4+1] = v.y; lt[k][c4+2] = v.z; lt[k][c4+3] = v.w;
    }
    __syncthreads();
    // dst row block = nt*64 (works for both halves: nt>=16 -> 1024 + (nt-16)*64 = nt*64)
    unsigned short* dst = WT + ((size_t)e * 2048 + nt * 64) * 1024 + kt * 64;
#pragma unroll
    for (int i = 0; i < 4; ++i) {
        int flat = i * 256 + t;
        int n = flat >> 4, kc = (flat & 15) * 4;
        unsigned int lo = (unsigned int)bf16_rne(lt[kc][n])   | ((unsigned int)bf16_rne(lt[kc+1][n]) << 16);
        unsigned int hi = (unsigned int)bf16_rne(lt[kc+2][n]) | ((unsigned int)bf16_rne(lt[kc+3][n]) << 16);
        *(uint2*)(dst + (size_t)n * 1024 + kc) = make_uint2(lo, hi);
    }
}

// ---------------- cvt2: W2 fp32 [e][2048k][1024d] -> W2T bf16 [e][1024n][2048k] ----------------
__global__ __launch_bounds__(256) void k_cvt2(const float* __restrict__ W2,
                                              unsigned short* __restrict__ WT) {
    __shared__ float lt[64][65];
    int e = blockIdx.z, nt = blockIdx.y, kt = blockIdx.x;
    const float* src = W2 + (size_t)e * FF * DM + (size_t)(kt * 64) * DM + nt * 64;
    int t = threadIdx.x;
#pragma unroll
    for (int i = 0; i < 4; ++i) {
        int flat = i * 256 + t;
        int k = flat >> 4, c4 = (flat & 15) * 4;
        float4 v = *(const float4*)(src + (size_t)k * DM + c4);
        lt[k][c4] = v.x; lt[k][c4+1] = v.y; lt[k][c4+2] = v.z; lt[k][c4+3] = v.w;
    }
    __syncthreads();
    unsigned short* dst = WT + ((size_t)e * 1024 + nt * 64) * 2048 + kt * 64;
#pragma unroll
    for (int i = 0; i < 4; ++i) {
        int flat = i * 256 + t;
        int n = flat >> 4, kc = (flat & 15) * 4;
        unsigned int lo = (unsigned int)bf16_rne(lt[kc][n])   | ((unsigned int)bf16_rne(lt[kc+1][n]) << 16);
        unsigned int hi = (unsigned int)bf16_rne(lt[kc+2][n]) | ((unsigned int)bf16_rne(lt[kc+3][n]) << 16);
        *(uint2*)(dst + (size_t)n * 2048 + kc) = make_uint2(lo, hi);
    }
}

// ---------------- GEMM1: hh[:, h*1024 + c] = silu(X@W1a)*(X@W1g), m97-style ----------------
// BM=128 rows x 64 hh-cols (a+g => 128 B-rows), BK=64, 4 waves (2x2)
__global__ __launch_bounds__(256, 2) void k_gemm1(const unsigned short* __restrict__ xbf,
                                                  const unsigned short* __restrict__ W1T,
                                                  const float* __restrict__ b1,
                                                  const int* __restrict__ pair_tok,
                                                  const int* __restrict__ cnt_pad,
                                                  const int* __restrict__ off_pad,
                                                  unsigned short* __restrict__ hh, int h) {
    int e = blockIdx.z;
    if ((int)blockIdx.y * 128 >= cnt_pad[e]) return;
    int row0 = off_pad[e] + blockIdx.y * 128;
    int c0 = blockIdx.x * 64;
    const unsigned short* WTe = W1T + (size_t)e * 2048 * 1024;

    __shared__ unsigned short lA[128 * 64];
    __shared__ unsigned short lB[128 * 64];

    int t = threadIdx.x, w = t >> 6, l = t & 63;
    int wm = w >> 1, wn = w & 1;

    const unsigned short* asrc[4];
    const unsigned short* bsrc[4];
    unsigned short* adst[4];
    unsigned short* bdst[4];
    int c8 = ((l & 7) ^ (l >> 3)) * 8;   // pre-swizzled source chunk
#pragma unroll
    for (int q = 0; q < 4; ++q) {
        int r = w * 32 + q * 8 + (l >> 3);
        int tok = pair_tok[row0 + r];
        asrc[q] = xbf + (size_t)tok * DM + c8;
        adst[q] = lA + (w * 32 + q * 8) * 64;
        int bn = (r < 64) ? (c0 + r) : (1024 + c0 + (r - 64));   // a rows then g rows
        bsrc[q] = WTe + (size_t)bn * 1024 + c8;
        bdst[q] = lB + (w * 32 + q * 8) * 64;
    }

    f32x4 aca[4][2], acg[4][2];
#pragma unroll
    for (int m = 0; m < 4; ++m)
#pragma unroll
        for (int fn = 0; fn < 2; ++fn) { aca[m][fn] = (f32x4){0,0,0,0}; acg[m][fn] = (f32x4){0,0,0,0}; }

#pragma unroll
    for (int q = 0; q < 4; ++q) { gload16(asrc[q], adst[q]); gload16(bsrc[q], bdst[q]); }

    int lr = l & 15, kg = l >> 4;
    for (int kt = 0; kt < 16; ++kt) {
        __syncthreads();   // drains vmcnt: staged tile visible
#pragma unroll
        for (int ks = 0; ks < 2; ++ks) {
            int kc = (ks * 64 + kg * 16);
            bf16x8 af[4];
#pragma unroll
            for (int m = 0; m < 4; ++m) {
                int row = wm * 64 + m * 16 + lr;
                af[m] = *(const bf16x8*)((const char*)lA + row * 128 + (kc ^ ((row & 7) << 4)));
            }
#pragma unroll
            for (int fn = 0; fn < 2; ++fn) {
                int na = wn * 32 + fn * 16 + lr;
                bf16x8 ba = *(const bf16x8*)((const char*)lB + na * 128 + (kc ^ ((na & 7) << 4)));
                bf16x8 bg = *(const bf16x8*)((const char*)lB + (na + 64) * 128 + (kc ^ ((na & 7) << 4)));
#pragma unroll
                for (int m = 0; m < 4; ++m) {
                    aca[m][fn] = MFMA16(af[m], ba, aca[m][fn]);
                    acg[m][fn] = MFMA16(af[m], bg, acg[m][fn]);
                }
            }
        }
        __syncthreads();   // all reads done before restage
        if (kt < 15) {
#pragma unroll
            for (int q = 0; q < 4; ++q) {
                gload16(asrc[q] + (kt + 1) * 64, adst[q]);
                gload16(bsrc[q] + (kt + 1) * 64, bdst[q]);
            }
        }
    }
    // epilogue: SwiGLU, bf16 store
#pragma unroll
    for (int m = 0; m < 4; ++m)
#pragma unroll
        for (int fn = 0; fn < 2; ++fn) {
            int colh = h * 1024 + c0 + wn * 32 + fn * 16 + lr;   // hh col (0..2047)
            float ba1 = b1[e * F2 + colh], bg1 = b1[e * F2 + FF + colh];
#pragma unroll
            for (int j = 0; j < 4; ++j) {
                int row = wm * 64 + m * 16 + kg * 4 + j;
                float a = aca[m][fn][j] + ba1;
                float g = acg[m][fn][j] + bg1;
                float sg = a / (1.f + __expf(-a)) * g;
                hh[(size_t)(row0 + row) * FF + colh] = bf16_rne(sg);
            }
        }
}

// ---------------- GEMM2: out += w * (hh @ W2 + b2), m97-style, BN=128 ----------------
__global__ __launch_bounds__(256, 2) void k_gemm2(const unsigned short* __restrict__ hh,
                                                  const unsigned short* __restrict__ W2T,
                                                  const float* __restrict__ b2,
                                                  const int* __restrict__ pair_tok,
                                                  const float* __restrict__ pair_w,
                                                  const int* __restrict__ cnt_pad,
                                                  const int* __restrict__ off_pad,
                                                  float* __restrict__ out) {
    int e = blockIdx.z;
    if ((int)blockIdx.y * 128 >= cnt_pad[e]) return;
    int row0 = off_pad[e] + blockIdx.y * 128;
    int d0 = blockIdx.x * 128;
    const unsigned short* WTe = W2T + (size_t)e * 1024 * 2048;

    __shared__ unsigned short lA[128 * 64];
    __shared__ unsigned short lB[128 * 64];

    int t = threadIdx.x, w = t >> 6, l = t & 63;
    int wm = w >> 1, wn = w & 1;

    const unsigned short* asrc[4];
    const unsigned short* bsrc[4];
    unsigned short* adst[4];
    unsigned short* bdst[4];
    int c8 = ((l & 7) ^ (l >> 3)) * 8;
#pragma unroll
    for (int q = 0; q < 4; ++q) {
        int r = w * 32 + q * 8 + (l >> 3);
        asrc[q] = hh + (size_t)(row0 + r) * FF + c8;
        adst[q] = lA + (w * 32 + q * 8) * 64;
        bsrc[q] = WTe + (size_t)(d0 + r) * 2048 + c8;
        bdst[q] = lB + (w * 32 + q * 8) * 64;
    }

    f32x4 ac[4][4];
#pragma unroll
    for (int m = 0; m < 4; ++m)
#pragma unroll
        for (int fn = 0; fn < 4; ++fn) ac[m][fn] = (f32x4){0,0,0,0};

#pragma unroll
    for (int q = 0; q < 4; ++q) { gload16(asrc[q], adst[q]); gload16(bsrc[q], bdst[q]); }

    int lr = l & 15, kg = l >> 4;
    for (int kt = 0; kt < 32; ++kt) {
        __syncthreads();
#pragma unroll
        for (int ks = 0; ks < 2; ++ks) {
            int kc = (ks * 64 + kg * 16);
            bf16x8 af[4];
#pragma unroll
            for (int m = 0; m < 4; ++m) {
                int row = wm * 64 + m * 16 + lr;
                af[m] = *(const bf16x8*)((const char*)lA + row * 128 + (kc ^ ((row & 7) << 4)));
            }
#pragma unroll
            for (int fn = 0; fn < 4; ++fn) {
                int n = wn * 64 + fn * 16 + lr;
                bf16x8 bb = *(const bf16x8*)((const char*)lB + n * 128 + (kc ^ ((n & 7) << 4)));
#pragma unroll
                for (int m = 0; m < 4; ++m) ac[m][fn] = MFMA16(af[m], bb, ac[m][fn]);
            }
        }
        __syncthreads();
        if (kt < 31) {
#pragma unroll
            for (int q = 0; q < 4; ++q) {
                gload16(asrc[q] + (kt + 1) * 64, adst[q]);
                gload16(bsrc[q] + (kt + 1) * 64, bdst[q]);
            }
        }
    }
#pragma unroll
    for (int m = 0; m < 4; ++m)
#pragma unroll
        for (int fn = 0; fn < 4; ++fn) {
            int col = d0 + wn * 64 + fn * 16 + lr;
            float b2v = b2[e * DM + col];
#pragma unroll
            for (int j = 0; j < 4; ++j) {
                int row = wm * 64 + m * 16 + kg * 4 + j;
                int pr = row0 + row;
                int tok = pair_tok[pr];
                float wt = pair_w[pr];
                atomicAdd(out + (size_t)tok * DM + col, wt * (ac[m][fn][j] + b2v));
            }
        }
}

// ---------------- host ----------------
extern "C" void kernel_launch(void* const* d_in, const int* in_sizes, int n_in,
                              void* d_out, int out_size, void* d_ws, size_t ws_size,
                              hipStream_t stream) {
    const float* x  = (const float*)d_in[0];
    const float* Wg = (const float*)d_in[1];
    const float* W1 = (const float*)d_in[2];
    const float* b1 = (const float*)d_in[3];
    const float* W2 = (const float*)d_in[4];
    const float* b2 = (const float*)d_in[5];
    float* out = (float*)d_out;

    char* ws = (char*)d_ws;
    unsigned short* xbf = (unsigned short*)ws;                        // 8.39 MB
    unsigned short* hh  = (unsigned short*)(ws + 8388608);            // 37.75 MB
    unsigned short* WT  = (unsigned short*)(ws + 46137344);           // 33.55 MB (W1T half / W2T shared)
    int*   pair_tok = (int*)(ws + 79691776);
    float* pair_w   = (float*)(ws + 79728640);
    int*   te       = (int*)(ws + 79765504);
    float* tw       = (float*)(ws + 79798272);
    int*   cnt      = (int*)(ws + 79831040);
    int*   cur      = (int*)(ws + 79831072);
    int*   cnt_pad  = (int*)(ws + 79831104);
    int*   off_pad  = (int*)(ws + 79831136);

    hipMemsetAsync(d_out, 0, (size_t)out_size * sizeof(float), stream);
    hipMemsetAsync(cnt, 0, 64, stream);  // cnt + cur

    k_gate<<<NTOK, 64, 0, stream>>>(x, Wg, xbf, te, tw, cnt);
    k_offs<<<1, 256, 0, stream>>>(cnt, cnt_pad, off_pad, pair_tok, pair_w);
    k_place<<<(NTOK + 255) / 256, 256, 0, stream>>>(te, tw, off_pad, cur, pair_tok, pair_w, NTOK);

    for (int h = 0; h < 2; ++h) {
        k_cvt1<<<dim3(16, 32, 8), 256, 0, stream>>>(W1, WT, h);
        k_gemm1<<<dim3(16, 32, 8), 256, 0, stream>>>(xbf, WT, b1, pair_tok, cnt_pad, off_pad, hh, h);
    }
    k_cvt2<<<dim3(32, 16, 8), 256, 0, stream>>>(W2, WT);
    k_gemm2<<<dim3(8, 32, 8), 256, 0, stream>>>(hh, WT, b2, pair_tok, pair_w, cnt_pad, off_pad, out);
}